// Round 13
// baseline (353.582 us; speedup 1.0000x reference)
//
#include <hip/hip_runtime.h>
#include <math.h>

#define N_TOK 16384
#define DIM   768
#define FFD   3072
#define NEXP  8
#define EPSV  1e-6f

typedef __attribute__((ext_vector_type(4))) float f32x4;
typedef __attribute__((ext_vector_type(4))) unsigned short u16x4;
typedef __attribute__((ext_vector_type(8))) unsigned short u16x8;
typedef __attribute__((ext_vector_type(8))) __bf16 bf16x8;

static __device__ __forceinline__ unsigned short f2bf(float f) {
    unsigned int u = __builtin_bit_cast(unsigned int, f);
    u += 0x7fffu + ((u >> 16) & 1u);   // round-to-nearest-even
    return (unsigned short)(u >> 16);
}
static __device__ __forceinline__ bf16x8 as_bf(u16x8 v) {
    return __builtin_bit_cast(bf16x8, v);
}
static __device__ __forceinline__ void gload16(const void* g, void* l) {
    __builtin_amdgcn_global_load_lds(
        (const __attribute__((address_space(1))) unsigned int*)g,
        (__attribute__((address_space(3))) unsigned int*)l, 16, 0, 0);
}

// ---------------------------------------------------------------------------
// Fused setup kernel (R12-proven): [0,4608) wi conv, [4608,9216) wo conv,
// [9216,13312) RMSNorm+router with coalesced rw access.
// ---------------------------------------------------------------------------
__global__ __launch_bounds__(256) void k_setup(
    const float* __restrict__ wi, unsigned short* __restrict__ wib,
    const float* __restrict__ wo, unsigned short* __restrict__ wob,
    const float* __restrict__ x, const float* __restrict__ lnw,
    const float* __restrict__ rw,
    float* __restrict__ out_logits, float* __restrict__ out_eidx,
    float* __restrict__ topp, int* __restrict__ eidx,
    unsigned short* __restrict__ xn)
{
    __shared__ float tile[64][65];
    const int t = threadIdx.x;
    const int b = blockIdx.x;

    if (b < 9216) {
        const float* in;
        unsigned short* outp;
        int R, C, bb;
        if (b < 4608) { in = wi; outp = wib; R = DIM; C = FFD; bb = b; }
        else          { in = wo; outp = wob; R = FFD; C = DIM; bb = b - 4608; }
        const int bc = C >> 6, br = R >> 6;
        const int e = bb / (bc * br);
        const int rem = bb - e * bc * br;
        const int rt = rem / bc, ct = rem - rt * bc;
        {
            const int r = t >> 2, c4 = (t & 3) << 4;
            const float* src = in + ((size_t)e * R + rt * 64 + r) * C + ct * 64 + c4;
#pragma unroll
            for (int q = 0; q < 4; q++) {
                float4 f = ((const float4*)src)[q];
                tile[r][c4 + q * 4 + 0] = f.x;
                tile[r][c4 + q * 4 + 1] = f.y;
                tile[r][c4 + q * 4 + 2] = f.z;
                tile[r][c4 + q * 4 + 3] = f.w;
            }
        }
        __syncthreads();
        {
            const int c = t >> 2, r4 = (t & 3) << 4;
            u16x8 o0, o1;
#pragma unroll
            for (int j = 0; j < 8; j++)  o0[j] = f2bf(tile[r4 + j][c]);
#pragma unroll
            for (int j = 0; j < 8; j++)  o1[j] = f2bf(tile[r4 + 8 + j][c]);
            unsigned short* dst = outp + ((size_t)e * C + ct * 64 + c) * R + rt * 64 + r4;
            *(u16x8*)dst       = o0;
            *(u16x8*)(dst + 8) = o1;
        }
        return;
    }

    const int wid = t >> 6, lane = t & 63;
    const int tok = (b - 9216) * 4 + wid;
    const size_t base = (size_t)tok * DIM;
    float* xvs = ((float*)tile) + wid * 768;

    float4 v[3];
#pragma unroll
    for (int j = 0; j < 3; j++)
        v[j] = *(const float4*)(x + base + lane * 4 + j * 256);
    float ss = 0.f;
#pragma unroll
    for (int j = 0; j < 3; j++)
        ss += v[j].x * v[j].x + v[j].y * v[j].y + v[j].z * v[j].z + v[j].w * v[j].w;
#pragma unroll
    for (int s = 32; s > 0; s >>= 1) ss += __shfl_xor(ss, s);
    const float rstd = rsqrtf(ss * (1.0f / DIM) + EPSV);

#pragma unroll
    for (int j = 0; j < 3; j++) {
        float4 lw = *(const float4*)(lnw + lane * 4 + j * 256);
        float xv0 = v[j].x * rstd * lw.x, xv1 = v[j].y * rstd * lw.y;
        float xv2 = v[j].z * rstd * lw.z, xv3 = v[j].w * rstd * lw.w;
        u16x4 pk = { f2bf(xv0), f2bf(xv1), f2bf(xv2), f2bf(xv3) };
        *(u16x4*)(xn + base + lane * 4 + j * 256) = pk;
        float4 xq = { xv0, xv1, xv2, xv3 };
        *(float4*)&xvs[lane * 4 + j * 256] = xq;
    }
    __syncthreads();

    float rp = 0.f;
#pragma unroll 8
    for (int q = 0; q < 96; q++) {
        float xvv = xvs[(lane >> 3) + q * 8];
        float rwv = rw[q * 64 + lane];
        rp = fmaf(xvv, rwv, rp);
    }
    rp += __shfl_xor(rp, 8);
    rp += __shfl_xor(rp, 16);
    rp += __shfl_xor(rp, 32);
    if (lane < 8) out_logits[(size_t)tok * 8 + lane] = rp;

    float mx = rp; int am = lane & 7;
#pragma unroll
    for (int s = 1; s < 8; s <<= 1) {
        float o = __shfl_xor(mx, s);
        int  oa = __shfl_xor(am, s);
        if (o > mx || (o == mx && oa < am)) { mx = o; am = oa; }
    }
    float se = expf(rp - mx);
    se += __shfl_xor(se, 1);
    se += __shfl_xor(se, 2);
    se += __shfl_xor(se, 4);
    if (lane == 0) {
        topp[tok] = 1.0f / se;
        out_eidx[tok] = (float)am;
        eidx[tok] = am;
    }
}

// ---------------------------------------------------------------------------
__global__ __launch_bounds__(256) void k_hist(
    const int* __restrict__ eidx, int* __restrict__ blkhist)
{
    __shared__ int h[8];
    if (threadIdx.x < 8) h[threadIdx.x] = 0;
    __syncthreads();
    atomicAdd(&h[eidx[blockIdx.x * 256 + threadIdx.x]], 1);
    __syncthreads();
    if (threadIdx.x < 8) blkhist[blockIdx.x * 8 + threadIdx.x] = h[threadIdx.x];
}

// ---------------------------------------------------------------------------
// + resets the fused-GEMM work queue and ready flags each launch.
// ---------------------------------------------------------------------------
__global__ __launch_bounds__(512) void k_prefix(
    const int* __restrict__ blkhist, int* __restrict__ base,
    int* __restrict__ cnt, int* __restrict__ wq, int* __restrict__ flag)
{
    __shared__ int h[64 * 8];
    __shared__ int tot[8];
    __shared__ int eb[8];
    const int t = threadIdx.x;
    h[t] = blkhist[t];
    if (t == 0) *wq = 0;
    if (t < 256) flag[t] = 0;
    __syncthreads();
    const int b = t >> 3, e = t & 7;
    int s = 0;
    for (int bb = 0; bb < b; bb++) s += h[bb * 8 + e];
    if (b == 63) tot[e] = s + h[63 * 8 + e];
    __syncthreads();
    if (t == 0) {
        int p = 0;
#pragma unroll
        for (int q = 0; q < 8; q++) { eb[q] = p; p += tot[q]; }
    }
    __syncthreads();
    base[t] = eb[e] + s;
    if (t < 8) cnt[t] = tot[t];
}

// ---------------------------------------------------------------------------
__global__ __launch_bounds__(256) void k_scatter(
    const int* __restrict__ eidx, const int* __restrict__ base,
    int* __restrict__ list)
{
    __shared__ int wcnt[4][8];
    __shared__ int bb[8];
    const int t = threadIdx.x, b = blockIdx.x;
    const int lane = t & 63, wid = t >> 6;
    if (t < 8) bb[t] = base[b * 8 + t];
    const int tok = b * 256 + t;
    const int e = eidx[tok];
    int wrank = 0;
#pragma unroll
    for (int q = 0; q < 8; q++) {
        unsigned long long m = __ballot(e == q);
        if (e == q) wrank = __popcll(m & ((1ull << lane) - 1ull));
        if (lane == 0) wcnt[wid][q] = __popcll(m);
    }
    __syncthreads();
    int wbase = 0;
#pragma unroll
    for (int w = 0; w < 4; w++)
        if (w < wid) wbase += wcnt[w][e];
    list[bb[e] + wbase + wrank] = tok;
}

// ---------------------------------------------------------------------------
// FUSED grouped GEMM: one launch, dynamic work queue. Items [0,total1) are
// GEMM1 tiles (H = relu(Xn@WiT), 128x256, K=768); items [total1,total) are
// GEMM2 tiles (out = hs + topp*(H@WoT), 128x256, K=3072) gated on per-m-tile
// ready flags (12 GEMM1 n-tiles each). Queue order puts ALL GEMM1 items
// before any GEMM2 item -> a spinning consumer implies every producer is
// resident -> deadlock-free. GEMM1 work fills the slots GEMM2's 396 long
// tiles leave idle (R12: 77% fill, ~25-30us).
// Producer release: __syncthreads (vmcnt drain -> stores in L2) + one
// agent-RELEASE atomicAdd. Consumer: RELAXED polls (no per-poll L2 inv),
// then one agent-ACQUIRE load.
// ---------------------------------------------------------------------------
__global__ __launch_bounds__(256, 2) void k_ffn(
    const unsigned short* __restrict__ xn, const unsigned short* __restrict__ wib,
    const unsigned short* __restrict__ wob, unsigned short* __restrict__ Hb,
    const int* __restrict__ list, const int* __restrict__ cnt,
    const float* __restrict__ hs, const float* __restrict__ topp,
    float* __restrict__ out, int* __restrict__ wq, int* __restrict__ flag)
{
    __shared__ unsigned short Asm[128 * 64];      // 16 KB
    __shared__ unsigned short Bsm[256 * 64];      // 32 KB
    __shared__ int tokrow[128];
    __shared__ int spref[9];
    __shared__ int ebase[8];
    __shared__ int sitem;

    const int t = threadIdx.x, lane = t & 63, wid = t >> 6;
    if (t == 0) {
        int p = 0, qq = 0;
        spref[0] = 0;
#pragma unroll
        for (int e = 0; e < 8; e++) {
            ebase[e] = qq; qq += cnt[e];
            p += (cnt[e] + 127) >> 7;
            spref[e + 1] = p;
        }
    }
    __syncthreads();
    const int nmt = spref[8];
    const int total1 = nmt * 12;
    const int total  = total1 + nmt * 3;
    const int moff = (wid >> 1) * 64, noff = (wid & 1) * 128;
    const int lr = lane & 15, lq = lane >> 4;

    int arow[4], asub[4], brow[8], bsub[8];
#pragma unroll
    for (int i = 0; i < 4; i++) {
        int c = (wid * 4 + i) * 64 + lane;
        arow[i] = c >> 3;
        asub[i] = (c & 7) ^ (arow[i] & 7);
    }
#pragma unroll
    for (int i = 0; i < 8; i++) {
        int c = (wid * 8 + i) * 64 + lane;
        brow[i] = c >> 3;
        bsub[i] = (c & 7) ^ (brow[i] & 7);
    }

    for (;;) {
        __syncthreads();                 // prior tile done with LDS
        if (t == 0) sitem = atomicAdd(wq, 1);
        __syncthreads();
        const int item = sitem;
        if (item >= total) break;

        const bool g1 = (item < total1);
        const int it2 = g1 ? item : item - total1;
        const int per = g1 ? 12 : 3;
        const int gm = it2 / per, tn = it2 - gm * per;
        int e = 0;
        while (gm >= spref[e + 1]) e++;
        const int ce = cnt[e], eb = ebase[e];
        const int m0 = (gm - spref[e]) * 128, n0 = tn * 256;
        const int K = g1 ? DIM : FFD;
        const int BN = g1 ? FFD : DIM;

        if (!g1 && t == 0) {
            while (__hip_atomic_load(flag + gm, __ATOMIC_RELAXED,
                                     __HIP_MEMORY_SCOPE_AGENT) < 12)
                __builtin_amdgcn_s_sleep(8);
            (void)__hip_atomic_load(flag + gm, __ATOMIC_ACQUIRE,
                                    __HIP_MEMORY_SCOPE_AGENT);
        }
        if (t < 128)
            tokrow[t] = (m0 + t < ce) ? list[eb + m0 + t] : list[eb];
        __syncthreads();                 // tokrow ready + acquire block-wide

        const unsigned short* aP[4];
        const unsigned short* bP[8];
        const unsigned short* Bw = g1 ? wib : wob;
#pragma unroll
        for (int i = 0; i < 4; i++) {
            if (g1) {
                aP[i] = xn + (size_t)tokrow[arow[i]] * DIM + asub[i] * 8;
            } else {
                const int drow = (m0 + arow[i] < ce) ? (m0 + arow[i]) : (ce - 1);
                aP[i] = Hb + (size_t)(eb + drow) * FFD + asub[i] * 8;
            }
        }
#pragma unroll
        for (int i = 0; i < 8; i++)
            bP[i] = Bw + ((size_t)e * BN + n0 + brow[i]) * K + bsub[i] * 8;

        f32x4 acc[4][8];
#pragma unroll
        for (int mi = 0; mi < 4; mi++)
#pragma unroll
            for (int ni = 0; ni < 8; ni++) acc[mi][ni] = (f32x4){0, 0, 0, 0};

        for (int k0 = 0; k0 < K; k0 += 64) {
#pragma unroll
            for (int i = 0; i < 4; i++)
                gload16(aP[i] + k0, Asm + (wid * 4 + i) * 512);
#pragma unroll
            for (int i = 0; i < 8; i++)
                gload16(bP[i] + k0, Bsm + (wid * 8 + i) * 512);
            __syncthreads();
#pragma unroll
            for (int kf = 0; kf < 2; kf++) {
                const int phys = ((kf * 4 + lq) ^ (lr & 7)) * 8;
                bf16x8 af[4], bfr[8];
#pragma unroll
                for (int mi = 0; mi < 4; mi++)
                    af[mi] = as_bf(*(const u16x8*)&Asm[(moff + mi * 16 + lr) * 64 + phys]);
#pragma unroll
                for (int ni = 0; ni < 8; ni++)
                    bfr[ni] = as_bf(*(const u16x8*)&Bsm[(noff + ni * 16 + lr) * 64 + phys]);
#pragma unroll
                for (int mi = 0; mi < 4; mi++)
#pragma unroll
                    for (int ni = 0; ni < 8; ni++)
                        acc[mi][ni] = __builtin_amdgcn_mfma_f32_16x16x32_bf16(
                            af[mi], bfr[ni], acc[mi][ni], 0, 0, 0);
            }
            __syncthreads();
        }

        if (g1) {
#pragma unroll
            for (int mi = 0; mi < 4; mi++) {
#pragma unroll
                for (int r4 = 0; r4 < 4; r4++) {
                    const int row = moff + mi * 16 + lq * 4 + r4;
                    if (m0 + row < ce) {
                        unsigned short* hp = Hb + (size_t)(eb + m0 + row) * FFD + n0 + noff;
#pragma unroll
                        for (int ni = 0; ni < 8; ni++) {
                            float v = acc[mi][ni][r4];
                            v = v > 0.f ? v : 0.f;
                            hp[ni * 16 + lr] = f2bf(v);
                        }
                    }
                }
            }
            __syncthreads();             // vmcnt drain: all stores in L2
            if (t == 0)
                __hip_atomic_fetch_add(flag + gm, 1, __ATOMIC_RELEASE,
                                       __HIP_MEMORY_SCOPE_AGENT);
        } else {
#pragma unroll
            for (int mi = 0; mi < 4; mi++) {
#pragma unroll
                for (int r4 = 0; r4 < 4; r4++) {
                    const int row = moff + mi * 16 + lq * 4 + r4;
                    if (m0 + row < ce) {
                        const int tok = tokrow[row];
                        const float tp = topp[tok];
#pragma unroll
                        for (int ni = 0; ni < 8; ni++) {
                            const size_t idx = (size_t)tok * DIM + n0 + noff + ni * 16 + lr;
                            out[idx] = hs[idx] + tp * acc[mi][ni][r4];
                        }
                    }
                }
            }
        }
    }
}

// ---------------------------------------------------------------------------
// Fallback sequential GEMMs (R12-proven), used only if ws too small for wib.
// ---------------------------------------------------------------------------
__global__ __launch_bounds__(256, 2) void k_gemm1(
    const unsigned short* __restrict__ A, const unsigned short* __restrict__ Bw,
    const int* __restrict__ list, const int* __restrict__ cnt,
    unsigned short* __restrict__ Hout)
{
    constexpr int K   = DIM;
    constexpr int N   = FFD;
    constexpr int TNT = N / 256;
    __shared__ unsigned short Asm[128 * 64];
    __shared__ unsigned short Bsm[256 * 64];
    __shared__ int tokrow[128];
    __shared__ int spref[9];
    __shared__ int ebase[8];

    const int t = threadIdx.x, lane = t & 63, wid = t >> 6;
    if (t == 0) {
        int p = 0, qq = 0;
        spref[0] = 0;
#pragma unroll
        for (int e = 0; e < 8; e++) {
            ebase[e] = qq; qq += cnt[e];
            p += (cnt[e] + 127) >> 7;
            spref[e + 1] = p;
        }
    }
    __syncthreads();
    const int total = spref[8] * TNT;
    const int moff = (wid >> 1) * 64, noff = (wid & 1) * 128;
    const int lr = lane & 15, lq = lane >> 4;

    const int nwg = gridDim.x;
    const int xcd = blockIdx.x & 7, rr8 = blockIdx.x >> 3;
    const int qd = nwg >> 3, rm = nwg & 7;
    const int bid = (xcd < rm ? xcd * (qd + 1) : rm * (qd + 1) + (xcd - rm) * qd) + rr8;

    int arow[4], asub[4], brow[8], bsub[8];
#pragma unroll
    for (int i = 0; i < 4; i++) {
        int c = (wid * 4 + i) * 64 + lane;
        arow[i] = c >> 3;
        asub[i] = (c & 7) ^ (arow[i] & 7);
    }
#pragma unroll
    for (int i = 0; i < 8; i++) {
        int c = (wid * 8 + i) * 64 + lane;
        brow[i] = c >> 3;
        bsub[i] = (c & 7) ^ (brow[i] & 7);
    }

    for (int w = bid; w < total; w += gridDim.x) {
        const int gm = w / TNT, tn = w - gm * TNT;
        int e = 0;
        while (gm >= spref[e + 1]) e++;
        const int ce = cnt[e], eb = ebase[e];
        const int m0 = (gm - spref[e]) * 128, n0 = tn * 256;

        __syncthreads();
        if (t < 128)
            tokrow[t] = (m0 + t < ce) ? list[eb + m0 + t] : list[eb];
        __syncthreads();

        const unsigned short* aP[4];
        const unsigned short* bP[8];
#pragma unroll
        for (int i = 0; i < 4; i++)
            aP[i] = A + (size_t)tokrow[arow[i]] * K + asub[i] * 8;
#pragma unroll
        for (int i = 0; i < 8; i++)
            bP[i] = Bw + ((size_t)e * N + n0 + brow[i]) * K + bsub[i] * 8;

        f32x4 acc[4][8];
#pragma unroll
        for (int mi = 0; mi < 4; mi++)
#pragma unroll
            for (int ni = 0; ni < 8; ni++) acc[mi][ni] = (f32x4){0, 0, 0, 0};

        for (int k0 = 0; k0 < K; k0 += 64) {
#pragma unroll
            for (int i = 0; i < 4; i++)
                gload16(aP[i] + k0, Asm + (wid * 4 + i) * 512);
#pragma unroll
            for (int i = 0; i < 8; i++)
                gload16(bP[i] + k0, Bsm + (wid * 8 + i) * 512);
            __syncthreads();
#pragma unroll
            for (int kf = 0; kf < 2; kf++) {
                const int phys = ((kf * 4 + lq) ^ (lr & 7)) * 8;
                bf16x8 af[4], bfr[8];
#pragma unroll
                for (int mi = 0; mi < 4; mi++)
                    af[mi] = as_bf(*(const u16x8*)&Asm[(moff + mi * 16 + lr) * 64 + phys]);
#pragma unroll
                for (int ni = 0; ni < 8; ni++)
                    bfr[ni] = as_bf(*(const u16x8*)&Bsm[(noff + ni * 16 + lr) * 64 + phys]);
#pragma unroll
                for (int mi = 0; mi < 4; mi++)
#pragma unroll
                    for (int ni = 0; ni < 8; ni++)
                        acc[mi][ni] = __builtin_amdgcn_mfma_f32_16x16x32_bf16(
                            af[mi], bfr[ni], acc[mi][ni], 0, 0, 0);
            }
            __syncthreads();
        }

#pragma unroll
        for (int mi = 0; mi < 4; mi++) {
#pragma unroll
            for (int r4 = 0; r4 < 4; r4++) {
                const int row = moff + mi * 16 + lq * 4 + r4;
                if (m0 + row < ce) {
                    unsigned short* hp = Hout + (size_t)(eb + m0 + row) * FFD + n0 + noff;
#pragma unroll
                    for (int ni = 0; ni < 8; ni++) {
                        float v = acc[mi][ni][r4];
                        v = v > 0.f ? v : 0.f;
                        hp[ni * 16 + lr] = f2bf(v);
                    }
                }
            }
        }
    }
}

__global__ __launch_bounds__(256, 2) void k_gemm2(
    const unsigned short* __restrict__ A, const unsigned short* __restrict__ Bw,
    const int* __restrict__ list, const int* __restrict__ cnt,
    const float* __restrict__ hs, const float* __restrict__ topp,
    float* __restrict__ out)
{
    constexpr int K   = FFD;
    constexpr int N   = DIM;
    constexpr int TNT = N / 256;
    __shared__ unsigned short Asm[128 * 64];
    __shared__ unsigned short Bsm[256 * 64];
    __shared__ int tokrow[128];
    __shared__ int spref[9];
    __shared__ int ebase[8];

    const int t = threadIdx.x, lane = t & 63, wid = t >> 6;
    if (t == 0) {
        int p = 0, qq = 0;
        spref[0] = 0;
#pragma unroll
        for (int e = 0; e < 8; e++) {
            ebase[e] = qq; qq += cnt[e];
            p += (cnt[e] + 127) >> 7;
            spref[e + 1] = p;
        }
    }
    __syncthreads();
    const int total = spref[8] * TNT;
    const int moff = (wid >> 1) * 64, noff = (wid & 1) * 128;
    const int lr = lane & 15, lq = lane >> 4;

    const int nwg = gridDim.x;
    const int xcd = blockIdx.x & 7, rr8 = blockIdx.x >> 3;
    const int qd = nwg >> 3, rm = nwg & 7;
    const int bid = (xcd < rm ? xcd * (qd + 1) : rm * (qd + 1) + (xcd - rm) * qd) + rr8;

    int arow[4], asub[4], brow[8], bsub[8];
#pragma unroll
    for (int i = 0; i < 4; i++) {
        int c = (wid * 4 + i) * 64 + lane;
        arow[i] = c >> 3;
        asub[i] = (c & 7) ^ (arow[i] & 7);
    }
#pragma unroll
    for (int i = 0; i < 8; i++) {
        int c = (wid * 8 + i) * 64 + lane;
        brow[i] = c >> 3;
        bsub[i] = (c & 7) ^ (brow[i] & 7);
    }

    for (int w = bid; w < total; w += gridDim.x) {
        const int gm = w / TNT, tn = w - gm * TNT;
        int e = 0;
        while (gm >= spref[e + 1]) e++;
        const int ce = cnt[e], eb = ebase[e];
        const int m0 = (gm - spref[e]) * 128, n0 = tn * 256;

        __syncthreads();
        if (t < 128)
            tokrow[t] = (m0 + t < ce) ? list[eb + m0 + t] : list[eb];
        __syncthreads();

        const unsigned short* aP[4];
        const unsigned short* bP[8];
#pragma unroll
        for (int i = 0; i < 4; i++) {
            const int drow = (m0 + arow[i] < ce) ? (m0 + arow[i]) : (ce - 1);
            aP[i] = A + (size_t)(eb + drow) * K + asub[i] * 8;
        }
#pragma unroll
        for (int i = 0; i < 8; i++)
            bP[i] = Bw + ((size_t)e * N + n0 + brow[i]) * K + bsub[i] * 8;

        f32x4 acc[4][8];
#pragma unroll
        for (int mi = 0; mi < 4; mi++)
#pragma unroll
            for (int ni = 0; ni < 8; ni++) acc[mi][ni] = (f32x4){0, 0, 0, 0};

        for (int k0 = 0; k0 < K; k0 += 64) {
#pragma unroll
            for (int i = 0; i < 4; i++)
                gload16(aP[i] + k0, Asm + (wid * 4 + i) * 512);
#pragma unroll
            for (int i = 0; i < 8; i++)
                gload16(bP[i] + k0, Bsm + (wid * 8 + i) * 512);
            __syncthreads();
#pragma unroll
            for (int kf = 0; kf < 2; kf++) {
                const int phys = ((kf * 4 + lq) ^ (lr & 7)) * 8;
                bf16x8 af[4], bfr[8];
#pragma unroll
                for (int mi = 0; mi < 4; mi++)
                    af[mi] = as_bf(*(const u16x8*)&Asm[(moff + mi * 16 + lr) * 64 + phys]);
#pragma unroll
                for (int ni = 0; ni < 8; ni++)
                    bfr[ni] = as_bf(*(const u16x8*)&Bsm[(noff + ni * 16 + lr) * 64 + phys]);
#pragma unroll
                for (int mi = 0; mi < 4; mi++)
#pragma unroll
                    for (int ni = 0; ni < 8; ni++)
                        acc[mi][ni] = __builtin_amdgcn_mfma_f32_16x16x32_bf16(
                            af[mi], bfr[ni], acc[mi][ni], 0, 0, 0);
            }
            __syncthreads();
        }

#pragma unroll
        for (int mi = 0; mi < 4; mi++) {
#pragma unroll
            for (int r4 = 0; r4 < 4; r4++) {
                const int row = moff + mi * 16 + lq * 4 + r4;
                if (m0 + row < ce) {
                    const int tok = tokrow[row];
                    const float tp = topp[tok];
#pragma unroll
                    for (int ni = 0; ni < 8; ni++) {
                        const size_t idx = (size_t)tok * DIM + n0 + noff + ni * 16 + lr;
                        out[idx] = hs[idx] + tp * acc[mi][ni][r4];
                    }
                }
            }
        }
    }
}

// ---------------------------------------------------------------------------
extern "C" void kernel_launch(void* const* d_in, const int* in_sizes, int n_in,
                              void* d_out, int out_size, void* d_ws, size_t ws_size,
                              hipStream_t stream)
{
    const float* hs  = (const float*)d_in[0];
    const float* lnw = (const float*)d_in[1];
    const float* rw  = (const float*)d_in[2];
    const float* wi  = (const float*)d_in[3];
    const float* wo  = (const float*)d_in[4];

    float* out        = (float*)d_out;
    float* out_logits = out + (size_t)N_TOK * DIM;
    float* out_eidx   = out_logits + (size_t)N_TOK * NEXP;

    char* ws = (char*)d_ws;
    size_t off = 0;
    int*   cnt     = (int*)(ws + off);         off += 256;
    int*   list    = (int*)(ws + off);         off += (size_t)N_TOK * 4;
    float* topp    = (float*)(ws + off);       off += (size_t)N_TOK * 4;
    int*   eidx    = (int*)(ws + off);         off += (size_t)N_TOK * 4;
    int*   blkhist = (int*)(ws + off);         off += 4096;
    int*   base    = (int*)(ws + off);         off += 4096;
    int*   wq      = (int*)(ws + off);
    int*   flag    = wq + 16;                  off += 4096;
    unsigned short* xn  = (unsigned short*)(ws + off); off += (size_t)N_TOK * DIM * 2;
    unsigned short* Hb  = (unsigned short*)(ws + off); off += (size_t)N_TOK * FFD * 2;
    unsigned short* wob = (unsigned short*)(ws + off); off += (size_t)NEXP * FFD * DIM * 2;
    unsigned short* wib_ws = (unsigned short*)(ws + off);
    const size_t need = off + (size_t)NEXP * FFD * DIM * 2;
    const bool fused = (ws_size >= need);

    // Fused path: wib must NOT alias d_out (GEMM2 out-writes run concurrently
    // with GEMM1 wib-reads). Fallback: wib in d_out as before (sequential).
    unsigned short* wib = fused ? wib_ws : (unsigned short*)d_out;

    k_setup<<<13312, 256, 0, stream>>>(wi, wib, wo, wob, hs, lnw, rw,
                                       out_logits, out_eidx, topp, eidx, xn);
    k_hist<<<64, 256, 0, stream>>>(eidx, blkhist);
    k_prefix<<<1, 512, 0, stream>>>(blkhist, base, cnt, wq, flag);
    k_scatter<<<64, 256, 0, stream>>>(eidx, base, list);
    if (fused) {
        k_ffn<<<512, 256, 0, stream>>>(xn, wib, wob, Hb, list, cnt,
                                       hs, topp, out, wq, flag);
    } else {
        k_gemm1<<<1632, 256, 0, stream>>>(xn, wib, list, cnt, Hb);
        k_gemm2<<<408, 256, 0, stream>>>(Hb, wob, list, cnt, hs, topp, out);
    }
}

// Round 14
// 273.240 us; speedup vs baseline: 1.2940x; 1.2940x over previous
//
#include <hip/hip_runtime.h>
#include <math.h>

#define N_TOK 16384
#define DIM   768
#define FFD   3072
#define NEXP  8
#define EPSV  1e-6f

typedef __attribute__((ext_vector_type(4))) float f32x4;
typedef __attribute__((ext_vector_type(4))) unsigned short u16x4;
typedef __attribute__((ext_vector_type(8))) unsigned short u16x8;
typedef __attribute__((ext_vector_type(8))) __bf16 bf16x8;

static __device__ __forceinline__ unsigned short f2bf(float f) {
    unsigned int u = __builtin_bit_cast(unsigned int, f);
    u += 0x7fffu + ((u >> 16) & 1u);   // round-to-nearest-even
    return (unsigned short)(u >> 16);
}
static __device__ __forceinline__ bf16x8 as_bf(u16x8 v) {
    return __builtin_bit_cast(bf16x8, v);
}
static __device__ __forceinline__ void gload16(const void* g, void* l) {
    __builtin_amdgcn_global_load_lds(
        (const __attribute__((address_space(1))) unsigned int*)g,
        (__attribute__((address_space(3))) unsigned int*)l, 16, 0, 0);
}

// ---------------------------------------------------------------------------
// Fused setup kernel (R12-proven, ~HBM-bound: 376MB/6.3TBps ~= 60us):
// [0,4608) wi conv, [4608,9216) wo conv, [9216,13312) RMSNorm+router with
// coalesced rw access (rw[q*64+lane], one 256B segment/load).
// ---------------------------------------------------------------------------
__global__ __launch_bounds__(256) void k_setup(
    const float* __restrict__ wi, unsigned short* __restrict__ wib,
    const float* __restrict__ wo, unsigned short* __restrict__ wob,
    const float* __restrict__ x, const float* __restrict__ lnw,
    const float* __restrict__ rw,
    float* __restrict__ out_logits, float* __restrict__ out_eidx,
    float* __restrict__ topp, int* __restrict__ eidx,
    unsigned short* __restrict__ xn)
{
    __shared__ float tile[64][65];
    const int t = threadIdx.x;
    const int b = blockIdx.x;

    if (b < 9216) {
        const float* in;
        unsigned short* outp;
        int R, C, bb;
        if (b < 4608) { in = wi; outp = wib; R = DIM; C = FFD; bb = b; }
        else          { in = wo; outp = wob; R = FFD; C = DIM; bb = b - 4608; }
        const int bc = C >> 6, br = R >> 6;
        const int e = bb / (bc * br);
        const int rem = bb - e * bc * br;
        const int rt = rem / bc, ct = rem - rt * bc;
        {
            const int r = t >> 2, c4 = (t & 3) << 4;
            const float* src = in + ((size_t)e * R + rt * 64 + r) * C + ct * 64 + c4;
#pragma unroll
            for (int q = 0; q < 4; q++) {
                float4 f = ((const float4*)src)[q];
                tile[r][c4 + q * 4 + 0] = f.x;
                tile[r][c4 + q * 4 + 1] = f.y;
                tile[r][c4 + q * 4 + 2] = f.z;
                tile[r][c4 + q * 4 + 3] = f.w;
            }
        }
        __syncthreads();
        {
            const int c = t >> 2, r4 = (t & 3) << 4;
            u16x8 o0, o1;
#pragma unroll
            for (int j = 0; j < 8; j++)  o0[j] = f2bf(tile[r4 + j][c]);
#pragma unroll
            for (int j = 0; j < 8; j++)  o1[j] = f2bf(tile[r4 + 8 + j][c]);
            unsigned short* dst = outp + ((size_t)e * C + ct * 64 + c) * R + rt * 64 + r4;
            *(u16x8*)dst       = o0;
            *(u16x8*)(dst + 8) = o1;
        }
        return;
    }

    const int wid = t >> 6, lane = t & 63;
    const int tok = (b - 9216) * 4 + wid;
    const size_t base = (size_t)tok * DIM;
    float* xvs = ((float*)tile) + wid * 768;

    float4 v[3];
#pragma unroll
    for (int j = 0; j < 3; j++)
        v[j] = *(const float4*)(x + base + lane * 4 + j * 256);
    float ss = 0.f;
#pragma unroll
    for (int j = 0; j < 3; j++)
        ss += v[j].x * v[j].x + v[j].y * v[j].y + v[j].z * v[j].z + v[j].w * v[j].w;
#pragma unroll
    for (int s = 32; s > 0; s >>= 1) ss += __shfl_xor(ss, s);
    const float rstd = rsqrtf(ss * (1.0f / DIM) + EPSV);

#pragma unroll
    for (int j = 0; j < 3; j++) {
        float4 lw = *(const float4*)(lnw + lane * 4 + j * 256);
        float xv0 = v[j].x * rstd * lw.x, xv1 = v[j].y * rstd * lw.y;
        float xv2 = v[j].z * rstd * lw.z, xv3 = v[j].w * rstd * lw.w;
        u16x4 pk = { f2bf(xv0), f2bf(xv1), f2bf(xv2), f2bf(xv3) };
        *(u16x4*)(xn + base + lane * 4 + j * 256) = pk;
        float4 xq = { xv0, xv1, xv2, xv3 };
        *(float4*)&xvs[lane * 4 + j * 256] = xq;
    }
    __syncthreads();

    float rp = 0.f;
#pragma unroll 8
    for (int q = 0; q < 96; q++) {
        float xvv = xvs[(lane >> 3) + q * 8];
        float rwv = rw[q * 64 + lane];
        rp = fmaf(xvv, rwv, rp);
    }
    rp += __shfl_xor(rp, 8);
    rp += __shfl_xor(rp, 16);
    rp += __shfl_xor(rp, 32);
    if (lane < 8) out_logits[(size_t)tok * 8 + lane] = rp;

    float mx = rp; int am = lane & 7;
#pragma unroll
    for (int s = 1; s < 8; s <<= 1) {
        float o = __shfl_xor(mx, s);
        int  oa = __shfl_xor(am, s);
        if (o > mx || (o == mx && oa < am)) { mx = o; am = oa; }
    }
    float se = expf(rp - mx);
    se += __shfl_xor(se, 1);
    se += __shfl_xor(se, 2);
    se += __shfl_xor(se, 4);
    if (lane == 0) {
        topp[tok] = 1.0f / se;
        out_eidx[tok] = (float)am;
        eidx[tok] = am;
    }
}

// ---------------------------------------------------------------------------
__global__ __launch_bounds__(256) void k_hist(
    const int* __restrict__ eidx, int* __restrict__ blkhist)
{
    __shared__ int h[8];
    if (threadIdx.x < 8) h[threadIdx.x] = 0;
    __syncthreads();
    atomicAdd(&h[eidx[blockIdx.x * 256 + threadIdx.x]], 1);
    __syncthreads();
    if (threadIdx.x < 8) blkhist[blockIdx.x * 8 + threadIdx.x] = h[threadIdx.x];
}

// ---------------------------------------------------------------------------
__global__ __launch_bounds__(512) void k_prefix(
    const int* __restrict__ blkhist, int* __restrict__ base,
    int* __restrict__ cnt)
{
    __shared__ int h[64 * 8];
    __shared__ int tot[8];
    __shared__ int eb[8];
    const int t = threadIdx.x;
    h[t] = blkhist[t];
    __syncthreads();
    const int b = t >> 3, e = t & 7;
    int s = 0;
    for (int bb = 0; bb < b; bb++) s += h[bb * 8 + e];
    if (b == 63) tot[e] = s + h[63 * 8 + e];
    __syncthreads();
    if (t == 0) {
        int p = 0;
#pragma unroll
        for (int q = 0; q < 8; q++) { eb[q] = p; p += tot[q]; }
    }
    __syncthreads();
    base[t] = eb[e] + s;
    if (t < 8) cnt[t] = tot[t];
}

// ---------------------------------------------------------------------------
__global__ __launch_bounds__(256) void k_scatter(
    const int* __restrict__ eidx, const int* __restrict__ base,
    int* __restrict__ list)
{
    __shared__ int wcnt[4][8];
    __shared__ int bb[8];
    const int t = threadIdx.x, b = blockIdx.x;
    const int lane = t & 63, wid = t >> 6;
    if (t < 8) bb[t] = base[b * 8 + t];
    const int tok = b * 256 + t;
    const int e = eidx[tok];
    int wrank = 0;
#pragma unroll
    for (int q = 0; q < 8; q++) {
        unsigned long long m = __ballot(e == q);
        if (e == q) wrank = __popcll(m & ((1ull << lane) - 1ull));
        if (lane == 0) wcnt[wid][q] = __popcll(m);
    }
    __syncthreads();
    int wbase = 0;
#pragma unroll
    for (int w = 0; w < 4; w++)
        if (w < wid) wbase += wcnt[w][e];
    list[bb[e] + wbase + wrank] = tok;
}

// ---------------------------------------------------------------------------
// GEMM1 (R12-proven ~82us, ~957 TF): 128x256 tile, BK=64, single-buffer
// 2-barrier, A gathered via token list, H written in dense (permuted) order.
// The throughput comes from L2/L3 reuse (XCD swizzle) + 2-block/CU TLP;
// R13's fused-queue experiment (-locality) regressed FETCH 220->510MB.
// ---------------------------------------------------------------------------
__global__ __launch_bounds__(256, 2) void k_gemm1(
    const unsigned short* __restrict__ A, const unsigned short* __restrict__ Bw,
    const int* __restrict__ list, const int* __restrict__ cnt,
    unsigned short* __restrict__ Hout)
{
    constexpr int K   = DIM;
    constexpr int N   = FFD;
    constexpr int TNT = N / 256;                  // 12
    __shared__ unsigned short Asm[128 * 64];      // 16 KB
    __shared__ unsigned short Bsm[256 * 64];      // 32 KB
    __shared__ int tokrow[128];
    __shared__ int spref[9];
    __shared__ int ebase[8];

    const int t = threadIdx.x, lane = t & 63, wid = t >> 6;
    if (t == 0) {
        int p = 0, qq = 0;
        spref[0] = 0;
#pragma unroll
        for (int e = 0; e < 8; e++) {
            ebase[e] = qq; qq += cnt[e];
            p += (cnt[e] + 127) >> 7;
            spref[e + 1] = p;
        }
    }
    __syncthreads();
    const int total = spref[8] * TNT;
    const int moff = (wid >> 1) * 64, noff = (wid & 1) * 128;
    const int lr = lane & 15, lq = lane >> 4;

    const int nwg = gridDim.x;
    const int xcd = blockIdx.x & 7, rr8 = blockIdx.x >> 3;
    const int qd = nwg >> 3, rm = nwg & 7;
    const int bid = (xcd < rm ? xcd * (qd + 1) : rm * (qd + 1) + (xcd - rm) * qd) + rr8;

    int arow[4], asub[4], brow[8], bsub[8];
#pragma unroll
    for (int i = 0; i < 4; i++) {
        int c = (wid * 4 + i) * 64 + lane;
        arow[i] = c >> 3;
        asub[i] = (c & 7) ^ (arow[i] & 7);
    }
#pragma unroll
    for (int i = 0; i < 8; i++) {
        int c = (wid * 8 + i) * 64 + lane;
        brow[i] = c >> 3;
        bsub[i] = (c & 7) ^ (brow[i] & 7);
    }

    for (int w = bid; w < total; w += gridDim.x) {
        const int gm = w / TNT, tn = w - gm * TNT;
        int e = 0;
        while (gm >= spref[e + 1]) e++;
        const int ce = cnt[e], eb = ebase[e];
        const int m0 = (gm - spref[e]) * 128, n0 = tn * 256;

        __syncthreads();
        if (t < 128)
            tokrow[t] = (m0 + t < ce) ? list[eb + m0 + t] : list[eb];
        __syncthreads();

        const unsigned short* aP[4];
        const unsigned short* bP[8];
#pragma unroll
        for (int i = 0; i < 4; i++)
            aP[i] = A + (size_t)tokrow[arow[i]] * K + asub[i] * 8;
#pragma unroll
        for (int i = 0; i < 8; i++)
            bP[i] = Bw + ((size_t)e * N + n0 + brow[i]) * K + bsub[i] * 8;

        f32x4 acc[4][8];
#pragma unroll
        for (int mi = 0; mi < 4; mi++)
#pragma unroll
            for (int ni = 0; ni < 8; ni++) acc[mi][ni] = (f32x4){0, 0, 0, 0};

        for (int k0 = 0; k0 < K; k0 += 64) {
#pragma unroll
            for (int i = 0; i < 4; i++)
                gload16(aP[i] + k0, Asm + (wid * 4 + i) * 512);
#pragma unroll
            for (int i = 0; i < 8; i++)
                gload16(bP[i] + k0, Bsm + (wid * 8 + i) * 512);
            __syncthreads();
#pragma unroll
            for (int kf = 0; kf < 2; kf++) {
                const int phys = ((kf * 4 + lq) ^ (lr & 7)) * 8;
                bf16x8 af[4], bfr[8];
#pragma unroll
                for (int mi = 0; mi < 4; mi++)
                    af[mi] = as_bf(*(const u16x8*)&Asm[(moff + mi * 16 + lr) * 64 + phys]);
#pragma unroll
                for (int ni = 0; ni < 8; ni++)
                    bfr[ni] = as_bf(*(const u16x8*)&Bsm[(noff + ni * 16 + lr) * 64 + phys]);
#pragma unroll
                for (int mi = 0; mi < 4; mi++)
#pragma unroll
                    for (int ni = 0; ni < 8; ni++)
                        acc[mi][ni] = __builtin_amdgcn_mfma_f32_16x16x32_bf16(
                            af[mi], bfr[ni], acc[mi][ni], 0, 0, 0);
            }
            __syncthreads();
        }

#pragma unroll
        for (int mi = 0; mi < 4; mi++) {
#pragma unroll
            for (int r4 = 0; r4 < 4; r4++) {
                const int row = moff + mi * 16 + lq * 4 + r4;
                if (m0 + row < ce) {
                    unsigned short* hp = Hout + (size_t)(eb + m0 + row) * FFD + n0 + noff;
#pragma unroll
                    for (int ni = 0; ni < 8; ni++) {
                        float v = acc[mi][ni][r4];
                        v = v > 0.f ? v : 0.f;
                        hp[ni * 16 + lr] = f2bf(v);
                    }
                }
            }
        }
    }
}

// ---------------------------------------------------------------------------
// GEMM2 (R12-proven ~114us, ~688 TF; limited by 396 tiles / 512 slots):
// 128x256 tile, BK=64, single-buffer 2-barrier, dense A rows from permuted H.
// out[tok,:] = hs[tok,:] + topp[tok]*(Hperm @ WoT)
// ---------------------------------------------------------------------------
__global__ __launch_bounds__(256, 2) void k_gemm2(
    const unsigned short* __restrict__ A, const unsigned short* __restrict__ Bw,
    const int* __restrict__ list, const int* __restrict__ cnt,
    const float* __restrict__ hs, const float* __restrict__ topp,
    float* __restrict__ out)
{
    constexpr int K   = FFD;
    constexpr int N   = DIM;
    constexpr int TNT = N / 256;                  // 3
    __shared__ unsigned short Asm[128 * 64];      // 16 KB
    __shared__ unsigned short Bsm[256 * 64];      // 32 KB
    __shared__ int tokrow[128];
    __shared__ int spref[9];
    __shared__ int ebase[8];

    const int t = threadIdx.x, lane = t & 63, wid = t >> 6;
    if (t == 0) {
        int p = 0, qq = 0;
        spref[0] = 0;
#pragma unroll
        for (int e = 0; e < 8; e++) {
            ebase[e] = qq; qq += cnt[e];
            p += (cnt[e] + 127) >> 7;
            spref[e + 1] = p;
        }
    }
    __syncthreads();
    const int total = spref[8] * TNT;
    const int moff = (wid >> 1) * 64, noff = (wid & 1) * 128;
    const int lr = lane & 15, lq = lane >> 4;

    const int nwg = gridDim.x;
    const int xcd = blockIdx.x & 7, rr8 = blockIdx.x >> 3;
    const int qd = nwg >> 3, rm = nwg & 7;
    const int bid = (xcd < rm ? xcd * (qd + 1) : rm * (qd + 1) + (xcd - rm) * qd) + rr8;

    int arow[4], asub[4], brow[8], bsub[8];
#pragma unroll
    for (int i = 0; i < 4; i++) {
        int c = (wid * 4 + i) * 64 + lane;
        arow[i] = c >> 3;
        asub[i] = (c & 7) ^ (arow[i] & 7);
    }
#pragma unroll
    for (int i = 0; i < 8; i++) {
        int c = (wid * 8 + i) * 64 + lane;
        brow[i] = c >> 3;
        bsub[i] = (c & 7) ^ (brow[i] & 7);
    }

    for (int w = bid; w < total; w += gridDim.x) {
        const int gm = w / TNT, tn = w - gm * TNT;
        int e = 0;
        while (gm >= spref[e + 1]) e++;
        const int ce = cnt[e], eb = ebase[e];
        const int m0 = (gm - spref[e]) * 128, n0 = tn * 256;

        __syncthreads();
        if (t < 128)
            tokrow[t] = (m0 + t < ce) ? list[eb + m0 + t] : list[eb];
        __syncthreads();

        const unsigned short* aP[4];
        const unsigned short* bP[8];
#pragma unroll
        for (int i = 0; i < 4; i++) {
            const int drow = (m0 + arow[i] < ce) ? (m0 + arow[i]) : (ce - 1);
            aP[i] = A + (size_t)(eb + drow) * K + asub[i] * 8;
        }
#pragma unroll
        for (int i = 0; i < 8; i++)
            bP[i] = Bw + ((size_t)e * N + n0 + brow[i]) * K + bsub[i] * 8;

        f32x4 acc[4][8];
#pragma unroll
        for (int mi = 0; mi < 4; mi++)
#pragma unroll
            for (int ni = 0; ni < 8; ni++) acc[mi][ni] = (f32x4){0, 0, 0, 0};

        for (int k0 = 0; k0 < K; k0 += 64) {
#pragma unroll
            for (int i = 0; i < 4; i++)
                gload16(aP[i] + k0, Asm + (wid * 4 + i) * 512);
#pragma unroll
            for (int i = 0; i < 8; i++)
                gload16(bP[i] + k0, Bsm + (wid * 8 + i) * 512);
            __syncthreads();
#pragma unroll
            for (int kf = 0; kf < 2; kf++) {
                const int phys = ((kf * 4 + lq) ^ (lr & 7)) * 8;
                bf16x8 af[4], bfr[8];
#pragma unroll
                for (int mi = 0; mi < 4; mi++)
                    af[mi] = as_bf(*(const u16x8*)&Asm[(moff + mi * 16 + lr) * 64 + phys]);
#pragma unroll
                for (int ni = 0; ni < 8; ni++)
                    bfr[ni] = as_bf(*(const u16x8*)&Bsm[(noff + ni * 16 + lr) * 64 + phys]);
#pragma unroll
                for (int mi = 0; mi < 4; mi++)
#pragma unroll
                    for (int ni = 0; ni < 8; ni++)
                        acc[mi][ni] = __builtin_amdgcn_mfma_f32_16x16x32_bf16(
                            af[mi], bfr[ni], acc[mi][ni], 0, 0, 0);
            }
            __syncthreads();
        }

#pragma unroll
        for (int mi = 0; mi < 4; mi++) {
#pragma unroll
            for (int r4 = 0; r4 < 4; r4++) {
                const int row = moff + mi * 16 + lq * 4 + r4;
                if (m0 + row < ce) {
                    const int tok = tokrow[row];
                    const float tp = topp[tok];
#pragma unroll
                    for (int ni = 0; ni < 8; ni++) {
                        const size_t idx = (size_t)tok * DIM + n0 + noff + ni * 16 + lr;
                        out[idx] = hs[idx] + tp * acc[mi][ni][r4];
                    }
                }
            }
        }
    }
}

// ---------------------------------------------------------------------------
extern "C" void kernel_launch(void* const* d_in, const int* in_sizes, int n_in,
                              void* d_out, int out_size, void* d_ws, size_t ws_size,
                              hipStream_t stream)
{
    const float* hs  = (const float*)d_in[0];
    const float* lnw = (const float*)d_in[1];
    const float* rw  = (const float*)d_in[2];
    const float* wi  = (const float*)d_in[3];
    const float* wo  = (const float*)d_in[4];

    float* out        = (float*)d_out;
    float* out_logits = out + (size_t)N_TOK * DIM;
    float* out_eidx   = out_logits + (size_t)N_TOK * NEXP;

    char* ws = (char*)d_ws;
    size_t off = 0;
    int*   cnt     = (int*)(ws + off);         off += 256;
    int*   list    = (int*)(ws + off);         off += (size_t)N_TOK * 4;
    float* topp    = (float*)(ws + off);       off += (size_t)N_TOK * 4;
    int*   eidx    = (int*)(ws + off);         off += (size_t)N_TOK * 4;
    int*   blkhist = (int*)(ws + off);         off += 4096;
    int*   base    = (int*)(ws + off);         off += 4096;
    unsigned short* xn  = (unsigned short*)(ws + off); off += (size_t)N_TOK * DIM * 2;
    unsigned short* Hb  = (unsigned short*)(ws + off); off += (size_t)N_TOK * FFD * 2;
    unsigned short* wob = (unsigned short*)(ws + off);

    // wi^T (bf16 [e][F][D]) lives in d_out's first 37.75 MB: dead before
    // GEMM2's epilogue writes `out` (GEMMs run sequentially).
    unsigned short* wib = (unsigned short*)d_out;

    k_setup<<<13312, 256, 0, stream>>>(wi, wib, wo, wob, hs, lnw, rw,
                                       out_logits, out_eidx, topp, eidx, xn);
    k_hist<<<64, 256, 0, stream>>>(eidx, blkhist);
    k_prefix<<<1, 512, 0, stream>>>(blkhist, base, cnt);
    k_scatter<<<64, 256, 0, stream>>>(eidx, base, list);
    k_gemm1<<<1632, 256, 0, stream>>>(xn, wib, list, cnt, Hb);
    k_gemm2<<<408, 256, 0, stream>>>(Hb, wob, list, cnt, hs, topp, out);
}

// Round 15
// 265.786 us; speedup vs baseline: 1.3303x; 1.0280x over previous
//
#include <hip/hip_runtime.h>
#include <math.h>

#define N_TOK 16384
#define DIM   768
#define FFD   3072
#define NEXP  8
#define EPSV  1e-6f

typedef __attribute__((ext_vector_type(4))) float f32x4;
typedef __attribute__((ext_vector_type(4))) unsigned short u16x4;
typedef __attribute__((ext_vector_type(8))) unsigned short u16x8;
typedef __attribute__((ext_vector_type(8))) __bf16 bf16x8;

static __device__ __forceinline__ unsigned short f2bf(float f) {
    unsigned int u = __builtin_bit_cast(unsigned int, f);
    u += 0x7fffu + ((u >> 16) & 1u);   // round-to-nearest-even
    return (unsigned short)(u >> 16);
}
static __device__ __forceinline__ bf16x8 as_bf(u16x8 v) {
    return __builtin_bit_cast(bf16x8, v);
}
static __device__ __forceinline__ void gload16(const void* g, void* l) {
    __builtin_amdgcn_global_load_lds(
        (const __attribute__((address_space(1))) unsigned int*)g,
        (__attribute__((address_space(3))) unsigned int*)l, 16, 0, 0);
}

// ---------------------------------------------------------------------------
// Setup kernel: blocks [0,4608) convert wi (needed by gemm1), blocks
// [4608,8704) RMSNorm+router (coalesced rw). conv(wo) moved into k_gemm1's
// grid where its 151MB hides under gemm1's compute (gemm1 HBM ~1.4 of
// 6.3 TB/s -> headroom).
// ---------------------------------------------------------------------------
__global__ __launch_bounds__(256) void k_setup(
    const float* __restrict__ wi, unsigned short* __restrict__ wib,
    const float* __restrict__ x, const float* __restrict__ lnw,
    const float* __restrict__ rw,
    float* __restrict__ out_logits, float* __restrict__ out_eidx,
    float* __restrict__ topp, int* __restrict__ eidx,
    unsigned short* __restrict__ xn)
{
    __shared__ float tile[64][65];
    const int t = threadIdx.x;
    const int b = blockIdx.x;

    if (b < 4608) {
        // conv wi[e][DIM][FFD] f32 -> wib[e][FFD][DIM] bf16
        const int bc = FFD >> 6, br = DIM >> 6;
        const int e = b / (bc * br);
        const int rem = b - e * bc * br;
        const int rt = rem / bc, ct = rem - rt * bc;
        {
            const int r = t >> 2, c4 = (t & 3) << 4;
            const float* src = wi + ((size_t)e * DIM + rt * 64 + r) * FFD + ct * 64 + c4;
#pragma unroll
            for (int q = 0; q < 4; q++) {
                float4 f = ((const float4*)src)[q];
                tile[r][c4 + q * 4 + 0] = f.x;
                tile[r][c4 + q * 4 + 1] = f.y;
                tile[r][c4 + q * 4 + 2] = f.z;
                tile[r][c4 + q * 4 + 3] = f.w;
            }
        }
        __syncthreads();
        {
            const int c = t >> 2, r4 = (t & 3) << 4;
            u16x8 o0, o1;
#pragma unroll
            for (int j = 0; j < 8; j++)  o0[j] = f2bf(tile[r4 + j][c]);
#pragma unroll
            for (int j = 0; j < 8; j++)  o1[j] = f2bf(tile[r4 + 8 + j][c]);
            unsigned short* dst = wib + ((size_t)e * FFD + ct * 64 + c) * DIM + rt * 64 + r4;
            *(u16x8*)dst       = o0;
            *(u16x8*)(dst + 8) = o1;
        }
        return;
    }

    // ---- RMSNorm + router: one wave per token ----
    const int wid = t >> 6, lane = t & 63;
    const int tok = (b - 4608) * 4 + wid;
    const size_t base = (size_t)tok * DIM;
    float* xvs = ((float*)tile) + wid * 768;

    float4 v[3];
#pragma unroll
    for (int j = 0; j < 3; j++)
        v[j] = *(const float4*)(x + base + lane * 4 + j * 256);
    float ss = 0.f;
#pragma unroll
    for (int j = 0; j < 3; j++)
        ss += v[j].x * v[j].x + v[j].y * v[j].y + v[j].z * v[j].z + v[j].w * v[j].w;
#pragma unroll
    for (int s = 32; s > 0; s >>= 1) ss += __shfl_xor(ss, s);
    const float rstd = rsqrtf(ss * (1.0f / DIM) + EPSV);

#pragma unroll
    for (int j = 0; j < 3; j++) {
        float4 lw = *(const float4*)(lnw + lane * 4 + j * 256);
        float xv0 = v[j].x * rstd * lw.x, xv1 = v[j].y * rstd * lw.y;
        float xv2 = v[j].z * rstd * lw.z, xv3 = v[j].w * rstd * lw.w;
        u16x4 pk = { f2bf(xv0), f2bf(xv1), f2bf(xv2), f2bf(xv3) };
        *(u16x4*)(xn + base + lane * 4 + j * 256) = pk;
        float4 xq = { xv0, xv1, xv2, xv3 };
        *(float4*)&xvs[lane * 4 + j * 256] = xq;
    }
    __syncthreads();

    float rp = 0.f;
#pragma unroll 8
    for (int q = 0; q < 96; q++) {
        float xvv = xvs[(lane >> 3) + q * 8];
        float rwv = rw[q * 64 + lane];
        rp = fmaf(xvv, rwv, rp);
    }
    rp += __shfl_xor(rp, 8);
    rp += __shfl_xor(rp, 16);
    rp += __shfl_xor(rp, 32);
    if (lane < 8) out_logits[(size_t)tok * 8 + lane] = rp;

    float mx = rp; int am = lane & 7;
#pragma unroll
    for (int s = 1; s < 8; s <<= 1) {
        float o = __shfl_xor(mx, s);
        int  oa = __shfl_xor(am, s);
        if (o > mx || (o == mx && oa < am)) { mx = o; am = oa; }
    }
    float se = expf(rp - mx);
    se += __shfl_xor(se, 1);
    se += __shfl_xor(se, 2);
    se += __shfl_xor(se, 4);
    if (lane == 0) {
        topp[tok] = 1.0f / se;
        out_eidx[tok] = (float)am;
        eidx[tok] = am;
    }
}

// ---------------------------------------------------------------------------
__global__ __launch_bounds__(256) void k_hist(
    const int* __restrict__ eidx, int* __restrict__ blkhist)
{
    __shared__ int h[8];
    if (threadIdx.x < 8) h[threadIdx.x] = 0;
    __syncthreads();
    atomicAdd(&h[eidx[blockIdx.x * 256 + threadIdx.x]], 1);
    __syncthreads();
    if (threadIdx.x < 8) blkhist[blockIdx.x * 8 + threadIdx.x] = h[threadIdx.x];
}

// ---------------------------------------------------------------------------
// Scatter with inline prefix (k_prefix folded in: each block recomputes the
// 2KB 64x8 prefix locally; block 0 writes cnt). One fewer launch.
// ---------------------------------------------------------------------------
__global__ __launch_bounds__(256) void k_scatter(
    const int* __restrict__ eidx, const int* __restrict__ blkhist,
    int* __restrict__ list, int* __restrict__ cnt)
{
    __shared__ int h[64 * 8];
    __shared__ int tot[8];
    __shared__ int bb8[8];
    __shared__ int wcnt[4][8];
    const int t = threadIdx.x, b = blockIdx.x;
    const int lane = t & 63, wid = t >> 6;
    h[t] = blkhist[t];
    h[t + 256] = blkhist[t + 256];
    __syncthreads();
    if (t < 8) {
        int s = 0;
        for (int q = 0; q < 64; q++) s += h[q * 8 + t];
        tot[t] = s;
    }
    __syncthreads();
    if (t < 8) {
        int eb = 0;
        for (int q = 0; q < t; q++) eb += tot[q];
        int sp = 0;
        for (int q = 0; q < b; q++) sp += h[q * 8 + t];
        bb8[t] = eb + sp;
        if (b == 0) cnt[t] = tot[t];
    }
    const int tok = b * 256 + t;
    const int e = eidx[tok];
    int wrank = 0;
#pragma unroll
    for (int q = 0; q < 8; q++) {
        unsigned long long m = __ballot(e == q);
        if (e == q) wrank = __popcll(m & ((1ull << lane) - 1ull));
        if (lane == 0) wcnt[wid][q] = __popcll(m);
    }
    __syncthreads();
    int wbase = 0;
#pragma unroll
    for (int w = 0; w < 4; w++)
        if (w < wid) wbase += wcnt[w][e];
    list[bb8[e] + wbase + wrank] = tok;
}

// ---------------------------------------------------------------------------
// GEMM1 + hidden conv(wo): blocks [0,1632) are the proven 128x256 BK=64
// single-buffer 2-barrier grouped-GEMM tiles (hardcoded nwg=1632 swizzle);
// blocks [1632,6240) convert wo[e][FFD][DIM] -> wob[e][DIM][FFD] bf16,
// reusing Bsm as the transpose tile. The conv blocks' 151MB of HBM traffic
// hides under gemm1's compute phase (gemm1 has ~5TB/s BW headroom); gemm2
// (launched after) sees a completed wob by stream order.
// ---------------------------------------------------------------------------
__global__ __launch_bounds__(256, 2) void k_gemm1(
    const unsigned short* __restrict__ A, const unsigned short* __restrict__ Bw,
    const int* __restrict__ list, const int* __restrict__ cnt,
    unsigned short* __restrict__ Hout,
    const float* __restrict__ wo, unsigned short* __restrict__ wob)
{
    constexpr int K   = DIM;
    constexpr int N   = FFD;
    constexpr int TNT = N / 256;                  // 12
    constexpr int NWG = 1632;                     // tile-block count
    __shared__ unsigned short Asm[128 * 64];      // 16 KB
    __shared__ unsigned short Bsm[256 * 64];      // 32 KB
    __shared__ int tokrow[128];
    __shared__ int spref[9];
    __shared__ int ebase[8];

    const int t = threadIdx.x, lane = t & 63, wid = t >> 6;

    if (blockIdx.x >= NWG) {
        // ---- conv wo[e][FFD][DIM] f32 -> wob[e][DIM][FFD] bf16 ----
        float (*tile)[65] = reinterpret_cast<float(*)[65]>(Bsm);  // 16.6KB<=32KB
        const int bb = blockIdx.x - NWG;
        const int bc = DIM >> 6, br = FFD >> 6;    // 12, 48
        const int e = bb / (bc * br);
        const int rem = bb - e * bc * br;
        const int rt = rem / bc, ct = rem - rt * bc;
        {
            const int r = t >> 2, c4 = (t & 3) << 4;
            const float* src = wo + ((size_t)e * FFD + rt * 64 + r) * DIM + ct * 64 + c4;
#pragma unroll
            for (int q = 0; q < 4; q++) {
                float4 f = ((const float4*)src)[q];
                tile[r][c4 + q * 4 + 0] = f.x;
                tile[r][c4 + q * 4 + 1] = f.y;
                tile[r][c4 + q * 4 + 2] = f.z;
                tile[r][c4 + q * 4 + 3] = f.w;
            }
        }
        __syncthreads();
        {
            const int c = t >> 2, r4 = (t & 3) << 4;
            u16x8 o0, o1;
#pragma unroll
            for (int j = 0; j < 8; j++)  o0[j] = f2bf(tile[r4 + j][c]);
#pragma unroll
            for (int j = 0; j < 8; j++)  o1[j] = f2bf(tile[r4 + 8 + j][c]);
            unsigned short* dst = wob + ((size_t)e * DIM + ct * 64 + c) * FFD + rt * 64 + r4;
            *(u16x8*)dst       = o0;
            *(u16x8*)(dst + 8) = o1;
        }
        return;
    }

    if (t == 0) {
        int p = 0, qq = 0;
        spref[0] = 0;
#pragma unroll
        for (int e = 0; e < 8; e++) {
            ebase[e] = qq; qq += cnt[e];
            p += (cnt[e] + 127) >> 7;
            spref[e + 1] = p;
        }
    }
    __syncthreads();
    const int total = spref[8] * TNT;
    const int moff = (wid >> 1) * 64, noff = (wid & 1) * 128;
    const int lr = lane & 15, lq = lane >> 4;

    // bijective XCD swizzle over the NWG tile blocks (NWG%8==0)
    const int xcd = blockIdx.x & 7, rr8 = blockIdx.x >> 3;
    const int bid = xcd * (NWG >> 3) + rr8;

    int arow[4], asub[4], brow[8], bsub[8];
#pragma unroll
    for (int i = 0; i < 4; i++) {
        int c = (wid * 4 + i) * 64 + lane;
        arow[i] = c >> 3;
        asub[i] = (c & 7) ^ (arow[i] & 7);
    }
#pragma unroll
    for (int i = 0; i < 8; i++) {
        int c = (wid * 8 + i) * 64 + lane;
        brow[i] = c >> 3;
        bsub[i] = (c & 7) ^ (brow[i] & 7);
    }

    for (int w = bid; w < total; w += NWG) {
        const int gm = w / TNT, tn = w - gm * TNT;
        int e = 0;
        while (gm >= spref[e + 1]) e++;
        const int ce = cnt[e], eb = ebase[e];
        const int m0 = (gm - spref[e]) * 128, n0 = tn * 256;

        __syncthreads();
        if (t < 128)
            tokrow[t] = (m0 + t < ce) ? list[eb + m0 + t] : list[eb];
        __syncthreads();

        const unsigned short* aP[4];
        const unsigned short* bP[8];
#pragma unroll
        for (int i = 0; i < 4; i++)
            aP[i] = A + (size_t)tokrow[arow[i]] * K + asub[i] * 8;
#pragma unroll
        for (int i = 0; i < 8; i++)
            bP[i] = Bw + ((size_t)e * N + n0 + brow[i]) * K + bsub[i] * 8;

        f32x4 acc[4][8];
#pragma unroll
        for (int mi = 0; mi < 4; mi++)
#pragma unroll
            for (int ni = 0; ni < 8; ni++) acc[mi][ni] = (f32x4){0, 0, 0, 0};

        for (int k0 = 0; k0 < K; k0 += 64) {
#pragma unroll
            for (int i = 0; i < 4; i++)
                gload16(aP[i] + k0, Asm + (wid * 4 + i) * 512);
#pragma unroll
            for (int i = 0; i < 8; i++)
                gload16(bP[i] + k0, Bsm + (wid * 8 + i) * 512);
            __syncthreads();
#pragma unroll
            for (int kf = 0; kf < 2; kf++) {
                const int phys = ((kf * 4 + lq) ^ (lr & 7)) * 8;
                bf16x8 af[4], bfr[8];
#pragma unroll
                for (int mi = 0; mi < 4; mi++)
                    af[mi] = as_bf(*(const u16x8*)&Asm[(moff + mi * 16 + lr) * 64 + phys]);
#pragma unroll
                for (int ni = 0; ni < 8; ni++)
                    bfr[ni] = as_bf(*(const u16x8*)&Bsm[(noff + ni * 16 + lr) * 64 + phys]);
#pragma unroll
                for (int mi = 0; mi < 4; mi++)
#pragma unroll
                    for (int ni = 0; ni < 8; ni++)
                        acc[mi][ni] = __builtin_amdgcn_mfma_f32_16x16x32_bf16(
                            af[mi], bfr[ni], acc[mi][ni], 0, 0, 0);
            }
            __syncthreads();
        }

#pragma unroll
        for (int mi = 0; mi < 4; mi++) {
#pragma unroll
            for (int r4 = 0; r4 < 4; r4++) {
                const int row = moff + mi * 16 + lq * 4 + r4;
                if (m0 + row < ce) {
                    unsigned short* hp = Hout + (size_t)(eb + m0 + row) * FFD + n0 + noff;
#pragma unroll
                    for (int ni = 0; ni < 8; ni++) {
                        float v = acc[mi][ni][r4];
                        v = v > 0.f ? v : 0.f;
                        hp[ni * 16 + lr] = f2bf(v);
                    }
                }
            }
        }
    }
}

// ---------------------------------------------------------------------------
// GEMM2 (R12-proven ~113us): 128x256 tile, BK=64, single-buffer 2-barrier,
// dense A rows from permuted H.
// out[tok,:] = hs[tok,:] + topp[tok]*(Hperm @ WoT)
// ---------------------------------------------------------------------------
__global__ __launch_bounds__(256, 2) void k_gemm2(
    const unsigned short* __restrict__ A, const unsigned short* __restrict__ Bw,
    const int* __restrict__ list, const int* __restrict__ cnt,
    const float* __restrict__ hs, const float* __restrict__ topp,
    float* __restrict__ out)
{
    constexpr int K   = FFD;
    constexpr int N   = DIM;
    constexpr int TNT = N / 256;                  // 3
    __shared__ unsigned short Asm[128 * 64];      // 16 KB
    __shared__ unsigned short Bsm[256 * 64];      // 32 KB
    __shared__ int tokrow[128];
    __shared__ int spref[9];
    __shared__ int ebase[8];

    const int t = threadIdx.x, lane = t & 63, wid = t >> 6;
    if (t == 0) {
        int p = 0, qq = 0;
        spref[0] = 0;
#pragma unroll
        for (int e = 0; e < 8; e++) {
            ebase[e] = qq; qq += cnt[e];
            p += (cnt[e] + 127) >> 7;
            spref[e + 1] = p;
        }
    }
    __syncthreads();
    const int total = spref[8] * TNT;
    const int moff = (wid >> 1) * 64, noff = (wid & 1) * 128;
    const int lr = lane & 15, lq = lane >> 4;

    const int nwg = gridDim.x;
    const int xcd = blockIdx.x & 7, rr8 = blockIdx.x >> 3;
    const int qd = nwg >> 3, rm = nwg & 7;
    const int bid = (xcd < rm ? xcd * (qd + 1) : rm * (qd + 1) + (xcd - rm) * qd) + rr8;

    int arow[4], asub[4], brow[8], bsub[8];
#pragma unroll
    for (int i = 0; i < 4; i++) {
        int c = (wid * 4 + i) * 64 + lane;
        arow[i] = c >> 3;
        asub[i] = (c & 7) ^ (arow[i] & 7);
    }
#pragma unroll
    for (int i = 0; i < 8; i++) {
        int c = (wid * 8 + i) * 64 + lane;
        brow[i] = c >> 3;
        bsub[i] = (c & 7) ^ (brow[i] & 7);
    }

    for (int w = bid; w < total; w += gridDim.x) {
        const int gm = w / TNT, tn = w - gm * TNT;
        int e = 0;
        while (gm >= spref[e + 1]) e++;
        const int ce = cnt[e], eb = ebase[e];
        const int m0 = (gm - spref[e]) * 128, n0 = tn * 256;

        __syncthreads();
        if (t < 128)
            tokrow[t] = (m0 + t < ce) ? list[eb + m0 + t] : list[eb];
        __syncthreads();

        const unsigned short* aP[4];
        const unsigned short* bP[8];
#pragma unroll
        for (int i = 0; i < 4; i++) {
            const int drow = (m0 + arow[i] < ce) ? (m0 + arow[i]) : (ce - 1);
            aP[i] = A + (size_t)(eb + drow) * K + asub[i] * 8;
        }
#pragma unroll
        for (int i = 0; i < 8; i++)
            bP[i] = Bw + ((size_t)e * N + n0 + brow[i]) * K + bsub[i] * 8;

        f32x4 acc[4][8];
#pragma unroll
        for (int mi = 0; mi < 4; mi++)
#pragma unroll
            for (int ni = 0; ni < 8; ni++) acc[mi][ni] = (f32x4){0, 0, 0, 0};

        for (int k0 = 0; k0 < K; k0 += 64) {
#pragma unroll
            for (int i = 0; i < 4; i++)
                gload16(aP[i] + k0, Asm + (wid * 4 + i) * 512);
#pragma unroll
            for (int i = 0; i < 8; i++)
                gload16(bP[i] + k0, Bsm + (wid * 8 + i) * 512);
            __syncthreads();
#pragma unroll
            for (int kf = 0; kf < 2; kf++) {
                const int phys = ((kf * 4 + lq) ^ (lr & 7)) * 8;
                bf16x8 af[4], bfr[8];
#pragma unroll
                for (int mi = 0; mi < 4; mi++)
                    af[mi] = as_bf(*(const u16x8*)&Asm[(moff + mi * 16 + lr) * 64 + phys]);
#pragma unroll
                for (int ni = 0; ni < 8; ni++)
                    bfr[ni] = as_bf(*(const u16x8*)&Bsm[(noff + ni * 16 + lr) * 64 + phys]);
#pragma unroll
                for (int mi = 0; mi < 4; mi++)
#pragma unroll
                    for (int ni = 0; ni < 8; ni++)
                        acc[mi][ni] = __builtin_amdgcn_mfma_f32_16x16x32_bf16(
                            af[mi], bfr[ni], acc[mi][ni], 0, 0, 0);
            }
            __syncthreads();
        }

#pragma unroll
        for (int mi = 0; mi < 4; mi++) {
#pragma unroll
            for (int r4 = 0; r4 < 4; r4++) {
                const int row = moff + mi * 16 + lq * 4 + r4;
                if (m0 + row < ce) {
                    const int tok = tokrow[row];
                    const float tp = topp[tok];
#pragma unroll
                    for (int ni = 0; ni < 8; ni++) {
                        const size_t idx = (size_t)tok * DIM + n0 + noff + ni * 16 + lr;
                        out[idx] = hs[idx] + tp * acc[mi][ni][r4];
                    }
                }
            }
        }
    }
}

// ---------------------------------------------------------------------------
extern "C" void kernel_launch(void* const* d_in, const int* in_sizes, int n_in,
                              void* d_out, int out_size, void* d_ws, size_t ws_size,
                              hipStream_t stream)
{
    const float* hs  = (const float*)d_in[0];
    const float* lnw = (const float*)d_in[1];
    const float* rw  = (const float*)d_in[2];
    const float* wi  = (const float*)d_in[3];
    const float* wo  = (const float*)d_in[4];

    float* out        = (float*)d_out;
    float* out_logits = out + (size_t)N_TOK * DIM;
    float* out_eidx   = out_logits + (size_t)N_TOK * NEXP;

    char* ws = (char*)d_ws;
    size_t off = 0;
    int*   cnt     = (int*)(ws + off);         off += 256;
    int*   list    = (int*)(ws + off);         off += (size_t)N_TOK * 4;
    float* topp    = (float*)(ws + off);       off += (size_t)N_TOK * 4;
    int*   eidx    = (int*)(ws + off);         off += (size_t)N_TOK * 4;
    int*   blkhist = (int*)(ws + off);         off += 4096;
    unsigned short* xn  = (unsigned short*)(ws + off); off += (size_t)N_TOK * DIM * 2;
    unsigned short* Hb  = (unsigned short*)(ws + off); off += (size_t)N_TOK * FFD * 2;
    unsigned short* wob = (unsigned short*)(ws + off);

    // wi^T (bf16 [e][F][D]) lives in d_out's first 37.75 MB: dead before
    // GEMM2's epilogue writes `out` (GEMMs run sequentially).
    unsigned short* wib = (unsigned short*)d_out;

    k_setup<<<8704, 256, 0, stream>>>(wi, wib, hs, lnw, rw,
                                      out_logits, out_eidx, topp, eidx, xn);
    k_hist<<<64, 256, 0, stream>>>(eidx, blkhist);
    k_scatter<<<64, 256, 0, stream>>>(eidx, blkhist, list, cnt);
    k_gemm1<<<6240, 256, 0, stream>>>(xn, wib, list, cnt, Hb, wo, wob);
    k_gemm2<<<408, 256, 0, stream>>>(Hb, wob, list, cnt, hs, topp, out);
}